// Round 1
// baseline (636.494 us; speedup 1.0000x reference)
//
#include <hip/hip_runtime.h>
#include <math.h>

// Problem constants (fixed by reference file)
#define LQ      37440
#define DMODEL  256
#define NHEADS  8
#define NLEV    4
#define NPTS    4
#define CHEAD   32

// -------------------------------------------------------------------------
// Tiled fp32 GEMM: C = A(MxK) @ B(KxN) + bias(N). BM=BN=64, BK=16,
// 256 threads, 4x4 micro-tile per thread. Requires M%64==0, N%64==0, K%16==0.
// -------------------------------------------------------------------------
__global__ __launch_bounds__(256) void gemm_bias_kernel(
    const float* __restrict__ A, const float* __restrict__ B,
    const float* __restrict__ bias, float* __restrict__ C,
    int M, int N, int K)
{
    __shared__ float As[16][64];  // [k][m]
    __shared__ float Bs[16][64];  // [k][n]

    const int t  = threadIdx.x;
    const int bm = blockIdx.y * 64;
    const int bn = blockIdx.x * 64;
    const int tx = t & 15;        // 0..15 -> 4 cols each
    const int ty = t >> 4;        // 0..15 -> 4 rows each

    // A-stage mapping: each thread loads float4 along K
    const int am = t >> 2;          // 0..63 (row within tile)
    const int ak = (t & 3) << 2;    // 0,4,8,12
    // B-stage mapping: each thread loads float4 along N
    const int bk  = t >> 4;         // 0..15
    const int bn4 = (t & 15) << 2;  // 0..60

    float acc[4][4] = {};

    for (int k0 = 0; k0 < K; k0 += 16) {
        float4 av = *(const float4*)(A + (size_t)(bm + am) * K + k0 + ak);
        float4 bv = *(const float4*)(B + (size_t)(k0 + bk) * N + bn + bn4);
        __syncthreads();  // protect LDS from previous iteration's readers
        As[ak + 0][am] = av.x;
        As[ak + 1][am] = av.y;
        As[ak + 2][am] = av.z;
        As[ak + 3][am] = av.w;
        *(float4*)&Bs[bk][bn4] = bv;
        __syncthreads();
        #pragma unroll
        for (int k = 0; k < 16; ++k) {
            float4 a = *(const float4*)&As[k][ty << 2];
            float4 b = *(const float4*)&Bs[k][tx << 2];
            acc[0][0] += a.x * b.x; acc[0][1] += a.x * b.y; acc[0][2] += a.x * b.z; acc[0][3] += a.x * b.w;
            acc[1][0] += a.y * b.x; acc[1][1] += a.y * b.y; acc[1][2] += a.y * b.z; acc[1][3] += a.y * b.w;
            acc[2][0] += a.z * b.x; acc[2][1] += a.z * b.y; acc[2][2] += a.z * b.z; acc[2][3] += a.z * b.w;
            acc[3][0] += a.w * b.x; acc[3][1] += a.w * b.y; acc[3][2] += a.w * b.z; acc[3][3] += a.w * b.w;
        }
    }

    float4 bb = *(const float4*)(bias + bn + (tx << 2));
    #pragma unroll
    for (int i = 0; i < 4; ++i) {
        int r = bm + (ty << 2) + i;
        float4 o;
        o.x = acc[i][0] + bb.x;
        o.y = acc[i][1] + bb.y;
        o.z = acc[i][2] + bb.z;
        o.w = acc[i][3] + bb.w;
        *(float4*)(C + (size_t)r * N + bn + (tx << 2)) = o;
    }
}

// -------------------------------------------------------------------------
// Sampling kernel: per query, compute softmax(attn logits) per head (16),
// trilinear-sample 8h x 4l x 4p points from value, accumulate weighted sum
// into samp[q][h*32+c]. Block = 256 threads = 4 queries x (8 heads x 8
// channel-groups-of-4). Each corner read per wave is a coalesced 1KB row.
// -------------------------------------------------------------------------
__global__ __launch_bounds__(256) void sample_kernel(
    const float* __restrict__ refp,   // (LQ, 4, 3)
    const float* __restrict__ off,    // (LQ, 384)
    const float* __restrict__ attnl,  // (LQ, 128) logits
    const float* __restrict__ value,  // (LQ_in=37440, 256)
    float* __restrict__ samp)         // (LQ, 256)
{
    __shared__ float4 p0[4][128];  // fx, fy, fz, a(softmaxed)
    __shared__ int4   p1[4][128];  // x0, y0, z0, -
    __shared__ float  lg[4][128];  // logits

    const int t  = threadIdx.x;
    const int q0 = blockIdx.x * 4;

    const int   Sz[4]   = {32, 16, 8, 4};
    const float invS[4] = {1.f/32.f, 1.f/16.f, 1.f/8.f, 1.f/4.f};
    const int   St[4]   = {0, 32768, 36864, 37376};

    // Phase 1: per (q_local, h, l, p) grid-sample params
    #pragma unroll
    for (int pi = t; pi < 512; pi += 256) {
        int ql = pi >> 7;
        int hp = pi & 127;          // h*16 + l*4 + p
        int l  = (hp >> 2) & 3;
        int q  = q0 + ql;
        const float* o = off + q * 384 + hp * 3;
        const float* r = refp + q * 12 + l * 3;
        float S  = (float)Sz[l];
        float is = invS[l];
        // loc = ref + off/S (cubic levels: norm == S for all 3 axes)
        float ix = (r[0] + o[0] * is) * S - 0.5f;
        float iy = (r[1] + o[1] * is) * S - 0.5f;
        float iz = (r[2] + o[2] * is) * S - 0.5f;
        float xf = floorf(ix), yf = floorf(iy), zf = floorf(iz);
        p0[ql][hp] = make_float4(ix - xf, iy - yf, iz - zf, 0.f);
        p1[ql][hp] = make_int4((int)xf, (int)yf, (int)zf, 0);
        lg[ql][hp] = attnl[q * 128 + hp];
    }
    __syncthreads();

    // Phase 1b: softmax over 16 points per (q_local, head)
    #pragma unroll
    for (int pi = t; pi < 512; pi += 256) {
        int ql = pi >> 7;
        int hp = pi & 127;
        const float* L = &lg[ql][hp & 0x70];  // head base
        float m = L[0];
        #pragma unroll
        for (int j = 1; j < 16; ++j) m = fmaxf(m, L[j]);
        float s = 0.f;
        #pragma unroll
        for (int j = 0; j < 16; ++j) s += expf(L[j] - m);
        p0[ql][hp].w = expf(lg[ql][hp] - m) / s;
    }
    __syncthreads();

    // Phase 2: gather + weighted accumulate. 64 threads per query.
    const int ql   = t >> 6;
    const int lane = t & 63;
    const int h    = lane >> 3;
    const int cg   = (lane & 7) << 2;   // channel group base (4 floats)
    const int q    = q0 + ql;
    const float* vb = value + h * CHEAD + cg;

    float4 acc = make_float4(0.f, 0.f, 0.f, 0.f);

    #pragma unroll
    for (int l = 0; l < 4; ++l) {
        const int S  = Sz[l];
        const int st = St[l];
        #pragma unroll
        for (int p = 0; p < 4; ++p) {
            int hp = (h << 4) + (l << 2) + p;
            float4 P0 = p0[ql][hp];
            int4   P1 = p1[ql][hp];
            float fx = P0.x, fy = P0.y, fz = P0.z, a = P0.w;
            int x0 = P1.x, y0 = P1.y, z0 = P1.z;

            // edge weights with validity folded in; a folded into z
            float wx0 = (x0 >= 0  && x0 < S)     ? (1.f - fx) : 0.f;
            float wx1 = (x0 >= -1 && x0 < S - 1) ? fx         : 0.f;
            float wy0 = (y0 >= 0  && y0 < S)     ? (1.f - fy) : 0.f;
            float wy1 = (y0 >= -1 && y0 < S - 1) ? fy         : 0.f;
            float wz0 = (z0 >= 0  && z0 < S)     ? (1.f - fz) * a : 0.f;
            float wz1 = (z0 >= -1 && z0 < S - 1) ? fz * a         : 0.f;

            int cx0 = min(max(x0, 0), S - 1), cx1 = min(max(x0 + 1, 0), S - 1);
            int cy0 = min(max(y0, 0), S - 1), cy1 = min(max(y0 + 1, 0), S - 1);
            int cz0 = min(max(z0, 0), S - 1), cz1 = min(max(z0 + 1, 0), S - 1);

            // element offsets, scaled by 256 channels (row stride)
            int rz0 = (st + cz0 * S * S) << 8;
            int rz1 = (st + cz1 * S * S) << 8;
            int ry0 = (cy0 * S) << 8, ry1 = (cy1 * S) << 8;
            int rx0 = cx0 << 8,       rx1 = cx1 << 8;

            float w00 = wz0 * wy0, w01 = wz0 * wy1;
            float w10 = wz1 * wy0, w11 = wz1 * wy1;

            float4 v; float w;
            v = *(const float4*)(vb + rz0 + ry0 + rx0); w = w00 * wx0;
            acc.x += w * v.x; acc.y += w * v.y; acc.z += w * v.z; acc.w += w * v.w;
            v = *(const float4*)(vb + rz0 + ry0 + rx1); w = w00 * wx1;
            acc.x += w * v.x; acc.y += w * v.y; acc.z += w * v.z; acc.w += w * v.w;
            v = *(const float4*)(vb + rz0 + ry1 + rx0); w = w01 * wx0;
            acc.x += w * v.x; acc.y += w * v.y; acc.z += w * v.z; acc.w += w * v.w;
            v = *(const float4*)(vb + rz0 + ry1 + rx1); w = w01 * wx1;
            acc.x += w * v.x; acc.y += w * v.y; acc.z += w * v.z; acc.w += w * v.w;
            v = *(const float4*)(vb + rz1 + ry0 + rx0); w = w10 * wx0;
            acc.x += w * v.x; acc.y += w * v.y; acc.z += w * v.z; acc.w += w * v.w;
            v = *(const float4*)(vb + rz1 + ry0 + rx1); w = w10 * wx1;
            acc.x += w * v.x; acc.y += w * v.y; acc.z += w * v.z; acc.w += w * v.w;
            v = *(const float4*)(vb + rz1 + ry1 + rx0); w = w11 * wx0;
            acc.x += w * v.x; acc.y += w * v.y; acc.z += w * v.z; acc.w += w * v.w;
            v = *(const float4*)(vb + rz1 + ry1 + rx1); w = w11 * wx1;
            acc.x += w * v.x; acc.y += w * v.y; acc.z += w * v.z; acc.w += w * v.w;
        }
    }

    *(float4*)(samp + (size_t)q * DMODEL + h * CHEAD + cg) = acc;
}

// -------------------------------------------------------------------------
extern "C" void kernel_launch(void* const* d_in, const int* in_sizes, int n_in,
                              void* d_out, int out_size, void* d_ws, size_t ws_size,
                              hipStream_t stream) {
    const float* query = (const float*)d_in[0];   // (1, LQ, 256)
    const float* refp  = (const float*)d_in[1];   // (1, LQ, 4, 3)
    const float* inp   = (const float*)d_in[2];   // (1, 37440, 256)
    // d_in[3] spatial shapes, d_in[4] level starts: hardcoded
    const float* Wv   = (const float*)d_in[5];
    const float* bv   = (const float*)d_in[6];
    const float* Wo   = (const float*)d_in[7];
    const float* bo   = (const float*)d_in[8];
    const float* Wa   = (const float*)d_in[9];
    const float* ba   = (const float*)d_in[10];
    const float* Wout = (const float*)d_in[11];
    const float* bout = (const float*)d_in[12];

    float* ws    = (float*)d_ws;
    float* value = ws;                          // LQ*256  = 9,584,640 f
    float* off   = value + (size_t)LQ * 256;    // LQ*384  = 14,376,960 f
    float* attn  = off   + (size_t)LQ * 384;    // LQ*128  = 4,792,320 f
    float* samp  = attn  + (size_t)LQ * 128;    // LQ*256  = 9,584,640 f

    dim3 blk(256);
    // value = input_flatten @ W_value + b_value
    gemm_bias_kernel<<<dim3(256/64, LQ/64), blk, 0, stream>>>(inp, Wv, bv, value, LQ, 256, 256);
    // off = query @ W_off + b_off
    gemm_bias_kernel<<<dim3(384/64, LQ/64), blk, 0, stream>>>(query, Wo, bo, off, LQ, 384, 256);
    // attn logits = query @ W_attn + b_attn
    gemm_bias_kernel<<<dim3(128/64, LQ/64), blk, 0, stream>>>(query, Wa, ba, attn, LQ, 128, 256);
    // sampling + softmax + weighted sum
    sample_kernel<<<dim3(LQ/4), blk, 0, stream>>>(refp, off, attn, value, samp);
    // out = samp @ W_out + b_out
    gemm_bias_kernel<<<dim3(256/64, LQ/64), blk, 0, stream>>>(samp, Wout, bout, (float*)d_out, LQ, 256, 256);
}

// Round 3
// 496.575 us; speedup vs baseline: 1.2818x; 1.2818x over previous
//
#include <hip/hip_runtime.h>
#include <math.h>

// Problem constants (fixed by reference file)
#define LQ      37440
#define DMODEL  256
#define NHEADS  8
#define CHEAD   32
#define K_DIM   256

typedef __attribute__((ext_vector_type(8))) short short8;
typedef __attribute__((ext_vector_type(4))) short short4v;
typedef __attribute__((ext_vector_type(4))) float f32x4;

__device__ inline unsigned short bf16_rte(float f) {
    union { float f; unsigned u; } v; v.f = f;
    return (unsigned short)((v.u + 0x7fffu + ((v.u >> 16) & 1u)) >> 16);
}
__device__ inline float bf16_f(unsigned short s) {
    union { unsigned u; float f; } v; v.u = ((unsigned)s) << 16;
    return v.f;
}

// -------------------------------------------------------------------------
// prep_a: fp32 (n4*4 elems) -> hi/lo bf16 split
// -------------------------------------------------------------------------
__global__ __launch_bounds__(256) void prep_a(const float* __restrict__ A,
        unsigned short* __restrict__ hi, unsigned short* __restrict__ lo, int n4)
{
    int i = blockIdx.x * 256 + threadIdx.x;
    if (i >= n4) return;
    float4 v = ((const float4*)A)[i];
    short4v h, l;
    unsigned short s;
    s = bf16_rte(v.x); h.x = (short)s; l.x = (short)bf16_rte(v.x - bf16_f(s));
    s = bf16_rte(v.y); h.y = (short)s; l.y = (short)bf16_rte(v.y - bf16_f(s));
    s = bf16_rte(v.z); h.z = (short)s; l.z = (short)bf16_rte(v.z - bf16_f(s));
    s = bf16_rte(v.w); h.w = (short)s; l.w = (short)bf16_rte(v.w - bf16_f(s));
    ((short4v*)hi)[i] = h;
    ((short4v*)lo)[i] = l;
}

// -------------------------------------------------------------------------
// prep_b: B (K=256 x N fp32, row-major) -> Bt_hi/lo (N x 256 bf16)
// -------------------------------------------------------------------------
__global__ __launch_bounds__(256) void prep_b(const float* __restrict__ B,
        unsigned short* __restrict__ hi, unsigned short* __restrict__ lo, int N)
{
    int i = blockIdx.x * 256 + threadIdx.x;   // i over N*256
    int n = i >> 8, k = i & 255;
    if (n >= N) return;
    float v = B[(size_t)k * N + n];
    unsigned short h = bf16_rte(v);
    hi[(size_t)n * 256 + k] = h;
    lo[(size_t)n * 256 + k] = bf16_rte(v - bf16_f(h));
}

// -------------------------------------------------------------------------
// Split-bf16 MFMA GEMM: C = (A_hi+A_lo) @ (B_hi+B_lo)^T' + bias
// A: M x 256 (hi/lo bf16), Bt: N x 256 (hi/lo bf16, pre-transposed).
// BM=128, BN=64, BK=32. 256 threads = 4 waves, each wave 32x64 (2x4 tiles
// of mfma_f32_16x16x32_bf16). 3 MFMA per tile per k-step (drop lo*lo).
// Staging per k-step: As needs 2*128*32 shorts (16KB), Bs 2*64*32 (8KB);
// each thread stages 2 int4 per A array + 2 int4 from one B array = 96B.
// OUT_BF16: 0 -> fp32 out, 1 -> bf16 out.
// -------------------------------------------------------------------------
template<int OUT_BF16>
__global__ __launch_bounds__(256) void gemm_mfma(
    const unsigned short* __restrict__ A_hi, const unsigned short* __restrict__ A_lo,
    const unsigned short* __restrict__ Bt_hi, const unsigned short* __restrict__ Bt_lo,
    const float* __restrict__ bias, void* __restrict__ Cout, int M, int N)
{
    __shared__ __align__(16) unsigned short As[2][128][40];  // [hi/lo][m][k] pad->40
    __shared__ __align__(16) unsigned short Bs[2][64][40];   // [hi/lo][n][k]

    const int t    = threadIdx.x;
    const int bm   = blockIdx.y * 128;
    const int bn   = blockIdx.x * 64;
    const int w    = t >> 6;
    const int lane = t & 63;
    const int lm   = lane & 15;
    const int quad = lane >> 4;

    // A staging: thread t covers rows t>>1, k-chunk (t&1)*16 (two int4 per array)
    const int a_row = t >> 1;
    const int a_k   = (t & 1) << 4;      // 0 or 16 (shorts)
    // B staging: t>>7 selects hi/lo array; within 128 threads: row (t&127)>>1,
    // k-chunk (t&1)*16
    const int b_arr = t >> 7;
    const int b_row = (t & 127) >> 1;
    const int b_k   = (t & 1) << 4;

    int arow_g = bm + a_row; if (arow_g >= M) arow_g = M - 1;   // clamp edge
    const size_t a_off = (size_t)arow_g * K_DIM + a_k;
    const size_t b_off = (size_t)(bn + b_row) * K_DIM + b_k;
    const unsigned short* Bsrc = b_arr ? Bt_lo : Bt_hi;

    f32x4 acc[2][4];
    #pragma unroll
    for (int mt = 0; mt < 2; ++mt)
        #pragma unroll
        for (int nt = 0; nt < 4; ++nt)
            acc[mt][nt] = (f32x4){0.f, 0.f, 0.f, 0.f};

    for (int k0 = 0; k0 < K_DIM; k0 += 32) {
        int4 ah0 = *(const int4*)(A_hi + a_off + k0);
        int4 ah1 = *(const int4*)(A_hi + a_off + k0 + 8);
        int4 al0 = *(const int4*)(A_lo + a_off + k0);
        int4 al1 = *(const int4*)(A_lo + a_off + k0 + 8);
        int4 bv0 = *(const int4*)(Bsrc + b_off + k0);
        int4 bv1 = *(const int4*)(Bsrc + b_off + k0 + 8);
        __syncthreads();   // protect LDS from previous iteration's readers
        *(int4*)&As[0][a_row][a_k]     = ah0;
        *(int4*)&As[0][a_row][a_k + 8] = ah1;
        *(int4*)&As[1][a_row][a_k]     = al0;
        *(int4*)&As[1][a_row][a_k + 8] = al1;
        *(int4*)&Bs[b_arr][b_row][b_k]     = bv0;
        *(int4*)&Bs[b_arr][b_row][b_k + 8] = bv1;
        __syncthreads();

        short8 af[2][2], bf[2][4];
        #pragma unroll
        for (int mt = 0; mt < 2; ++mt) {
            af[0][mt] = *(const short8*)&As[0][w * 32 + mt * 16 + lm][quad * 8];
            af[1][mt] = *(const short8*)&As[1][w * 32 + mt * 16 + lm][quad * 8];
        }
        #pragma unroll
        for (int nt = 0; nt < 4; ++nt) {
            bf[0][nt] = *(const short8*)&Bs[0][nt * 16 + lm][quad * 8];
            bf[1][nt] = *(const short8*)&Bs[1][nt * 16 + lm][quad * 8];
        }
        #pragma unroll
        for (int mt = 0; mt < 2; ++mt)
            #pragma unroll
            for (int nt = 0; nt < 4; ++nt) {
                acc[mt][nt] = __builtin_amdgcn_mfma_f32_16x16x32_bf16(af[0][mt], bf[0][nt], acc[mt][nt], 0, 0, 0);
                acc[mt][nt] = __builtin_amdgcn_mfma_f32_16x16x32_bf16(af[1][mt], bf[0][nt], acc[mt][nt], 0, 0, 0);
                acc[mt][nt] = __builtin_amdgcn_mfma_f32_16x16x32_bf16(af[0][mt], bf[1][nt], acc[mt][nt], 0, 0, 0);
            }
    }

    float bv4[4];
    #pragma unroll
    for (int nt = 0; nt < 4; ++nt) bv4[nt] = bias[bn + nt * 16 + lm];

    #pragma unroll
    for (int mt = 0; mt < 2; ++mt)
        #pragma unroll
        for (int nt = 0; nt < 4; ++nt)
            #pragma unroll
            for (int r = 0; r < 4; ++r) {
                int row = bm + w * 32 + mt * 16 + quad * 4 + r;
                if (row < M) {
                    int col = bn + nt * 16 + lm;
                    float o = acc[mt][nt][r] + bv4[nt];
                    if (OUT_BF16)
                        ((unsigned short*)Cout)[(size_t)row * N + col] = bf16_rte(o);
                    else
                        ((float*)Cout)[(size_t)row * N + col] = o;
                }
            }
}

// -------------------------------------------------------------------------
// Sampling kernel: softmax + trilinear gather + weighted sum.
// off input bf16, attn logits fp32; outputs samp as hi/lo bf16 split.
// Block = 256 threads = 4 queries x (8 heads x 8 channel-groups-of-4).
// -------------------------------------------------------------------------
__global__ __launch_bounds__(256) void sample_kernel(
    const float* __restrict__ refp,            // (LQ, 4, 3)
    const unsigned short* __restrict__ off,    // (LQ, 384) bf16
    const float* __restrict__ attnl,           // (LQ, 128) fp32 logits
    const float* __restrict__ value,           // (37440, 256) fp32
    unsigned short* __restrict__ samp_hi,      // (LQ, 256) bf16
    unsigned short* __restrict__ samp_lo)      // (LQ, 256) bf16
{
    __shared__ float4 p0[4][128];  // fx, fy, fz, a(softmaxed)
    __shared__ int4   p1[4][128];  // x0, y0, z0, -
    __shared__ float  lg[4][128];  // logits

    const int t  = threadIdx.x;
    const int q0 = blockIdx.x * 4;

    const int   Sz[4]   = {32, 16, 8, 4};
    const float invS[4] = {1.f/32.f, 1.f/16.f, 1.f/8.f, 1.f/4.f};
    const int   St[4]   = {0, 32768, 36864, 37376};

    #pragma unroll
    for (int pi = t; pi < 512; pi += 256) {
        int ql = pi >> 7;
        int hp = pi & 127;          // h*16 + l*4 + p
        int l  = (hp >> 2) & 3;
        int q  = q0 + ql;
        const unsigned short* o = off + (size_t)q * 384 + hp * 3;
        const float* r = refp + q * 12 + l * 3;
        float S  = (float)Sz[l];
        float is = invS[l];
        float ix = (r[0] + bf16_f(o[0]) * is) * S - 0.5f;
        float iy = (r[1] + bf16_f(o[1]) * is) * S - 0.5f;
        float iz = (r[2] + bf16_f(o[2]) * is) * S - 0.5f;
        float xf = floorf(ix), yf = floorf(iy), zf = floorf(iz);
        p0[ql][hp] = make_float4(ix - xf, iy - yf, iz - zf, 0.f);
        p1[ql][hp] = make_int4((int)xf, (int)yf, (int)zf, 0);
        lg[ql][hp] = attnl[(size_t)q * 128 + hp];
    }
    __syncthreads();

    #pragma unroll
    for (int pi = t; pi < 512; pi += 256) {
        int ql = pi >> 7;
        int hp = pi & 127;
        const float* L = &lg[ql][hp & 0x70];
        float m = L[0];
        #pragma unroll
        for (int j = 1; j < 16; ++j) m = fmaxf(m, L[j]);
        float s = 0.f;
        #pragma unroll
        for (int j = 0; j < 16; ++j) s += expf(L[j] - m);
        p0[ql][hp].w = expf(lg[ql][hp] - m) / s;
    }
    __syncthreads();

    const int ql   = t >> 6;
    const int lane = t & 63;
    const int hh   = lane >> 3;
    const int cg   = (lane & 7) << 2;
    const int q    = q0 + ql;
    const float* vb = value + hh * CHEAD + cg;

    float4 acc = make_float4(0.f, 0.f, 0.f, 0.f);

    #pragma unroll
    for (int l = 0; l < 4; ++l) {
        const int S  = Sz[l];
        const int st = St[l];
        #pragma unroll
        for (int p = 0; p < 4; ++p) {
            int hp = (hh << 4) + (l << 2) + p;
            float4 P0 = p0[ql][hp];
            int4   P1 = p1[ql][hp];
            float fx = P0.x, fy = P0.y, fz = P0.z, a = P0.w;
            int x0 = P1.x, y0 = P1.y, z0 = P1.z;

            float wx0 = (x0 >= 0  && x0 < S)     ? (1.f - fx) : 0.f;
            float wx1 = (x0 >= -1 && x0 < S - 1) ? fx         : 0.f;
            float wy0 = (y0 >= 0  && y0 < S)     ? (1.f - fy) : 0.f;
            float wy1 = (y0 >= -1 && y0 < S - 1) ? fy         : 0.f;
            float wz0 = (z0 >= 0  && z0 < S)     ? (1.f - fz) * a : 0.f;
            float wz1 = (z0 >= -1 && z0 < S - 1) ? fz * a         : 0.f;

            int cx0 = min(max(x0, 0), S - 1), cx1 = min(max(x0 + 1, 0), S - 1);
            int cy0 = min(max(y0, 0), S - 1), cy1 = min(max(y0 + 1, 0), S - 1);
            int cz0 = min(max(z0, 0), S - 1), cz1 = min(max(z0 + 1, 0), S - 1);

            int rz0 = (st + cz0 * S * S) << 8;
            int rz1 = (st + cz1 * S * S) << 8;
            int ry0 = (cy0 * S) << 8, ry1 = (cy1 * S) << 8;
            int rx0 = cx0 << 8,       rx1 = cx1 << 8;

            float w00 = wz0 * wy0, w01 = wz0 * wy1;
            float w10 = wz1 * wy0, w11 = wz1 * wy1;

            float4 v; float w;
            v = *(const float4*)(vb + rz0 + ry0 + rx0); w = w00 * wx0;
            acc.x += w * v.x; acc.y += w * v.y; acc.z += w * v.z; acc.w += w * v.w;
            v = *(const float4*)(vb + rz0 + ry0 + rx1); w = w00 * wx1;
            acc.x += w * v.x; acc.y += w * v.y; acc.z += w * v.z; acc.w += w * v.w;
            v = *(const float4*)(vb + rz0 + ry1 + rx0); w = w01 * wx0;
            acc.x += w * v.x; acc.y += w * v.y; acc.z += w * v.z; acc.w += w * v.w;
            v = *(const float4*)(vb + rz0 + ry1 + rx1); w = w01 * wx1;
            acc.x += w * v.x; acc.y += w * v.y; acc.z += w * v.z; acc.w += w * v.w;
            v = *(const float4*)(vb + rz1 + ry0 + rx0); w = w10 * wx0;
            acc.x += w * v.x; acc.y += w * v.y; acc.z += w * v.z; acc.w += w * v.w;
            v = *(const float4*)(vb + rz1 + ry0 + rx1); w = w10 * wx1;
            acc.x += w * v.x; acc.y += w * v.y; acc.z += w * v.z; acc.w += w * v.w;
            v = *(const float4*)(vb + rz1 + ry1 + rx0); w = w11 * wx0;
            acc.x += w * v.x; acc.y += w * v.y; acc.z += w * v.z; acc.w += w * v.w;
            v = *(const float4*)(vb + rz1 + ry1 + rx1); w = w11 * wx1;
            acc.x += w * v.x; acc.y += w * v.y; acc.z += w * v.z; acc.w += w * v.w;
        }
    }

    // hi/lo split epilogue
    short4v oh, ol;
    unsigned short s;
    s = bf16_rte(acc.x); oh.x = (short)s; ol.x = (short)bf16_rte(acc.x - bf16_f(s));
    s = bf16_rte(acc.y); oh.y = (short)s; ol.y = (short)bf16_rte(acc.y - bf16_f(s));
    s = bf16_rte(acc.z); oh.z = (short)s; ol.z = (short)bf16_rte(acc.z - bf16_f(s));
    s = bf16_rte(acc.w); oh.w = (short)s; ol.w = (short)bf16_rte(acc.w - bf16_f(s));
    size_t oidx = (size_t)q * DMODEL + hh * CHEAD + cg;
    *(short4v*)(samp_hi + oidx) = oh;
    *(short4v*)(samp_lo + oidx) = ol;
}

// -------------------------------------------------------------------------
// Workspace plan (135.7 MB total, aliased regions):
//   region V: value fp32                      38.34 MB
//   region A: in_hi/in_lo -> off bf16 (after value GEMM)   38.34 MB
//   region B: q_hi/q_lo   -> s_hi/s_lo (after attn GEMM)   38.34 MB
//   attn fp32                                 19.17 MB
//   weight hi/lo buffers                       1.05 MB
// -------------------------------------------------------------------------
extern "C" void kernel_launch(void* const* d_in, const int* in_sizes, int n_in,
                              void* d_out, int out_size, void* d_ws, size_t ws_size,
                              hipStream_t stream) {
    const float* query = (const float*)d_in[0];
    const float* refp  = (const float*)d_in[1];
    const float* inp   = (const float*)d_in[2];
    const float* Wv   = (const float*)d_in[5];
    const float* bv   = (const float*)d_in[6];
    const float* Wo   = (const float*)d_in[7];
    const float* bo   = (const float*)d_in[8];
    const float* Wa   = (const float*)d_in[9];
    const float* ba   = (const float*)d_in[10];
    const float* Wout = (const float*)d_in[11];
    const float* bout = (const float*)d_in[12];

    char* p = (char*)d_ws;
    float* value = (float*)p;                   p += (size_t)LQ * 256 * 4;   // region V
    char* regionA = p;                          p += (size_t)LQ * 256 * 2 * 2;
    char* regionB = p;                          p += (size_t)LQ * 256 * 2 * 2;
    float* attn = (float*)p;                    p += (size_t)LQ * 128 * 4;
    unsigned short* Bv_hi = (unsigned short*)p; p += 256 * 256 * 2;
    unsigned short* Bv_lo = (unsigned short*)p; p += 256 * 256 * 2;
    unsigned short* Bo_hi = (unsigned short*)p; p += 384 * 256 * 2;
    unsigned short* Bo_lo = (unsigned short*)p; p += 384 * 256 * 2;
    unsigned short* Ba_hi = (unsigned short*)p; p += 128 * 256 * 2;
    unsigned short* Ba_lo = (unsigned short*)p; p += 128 * 256 * 2;
    unsigned short* Bw_hi = (unsigned short*)p; p += 256 * 256 * 2;
    unsigned short* Bw_lo = (unsigned short*)p; p += 256 * 256 * 2;

    unsigned short* in_hi = (unsigned short*)regionA;
    unsigned short* in_lo = in_hi + (size_t)LQ * 256;
    unsigned short* offb  = (unsigned short*)regionA;   // alias: after value GEMM
    unsigned short* q_hi  = (unsigned short*)regionB;
    unsigned short* q_lo  = q_hi + (size_t)LQ * 256;
    unsigned short* s_hi  = (unsigned short*)regionB;   // alias: after attn GEMM
    unsigned short* s_lo  = s_hi + (size_t)LQ * 256;

    const int n4 = LQ * 256 / 4;   // 2,396,160
    dim3 blk(256);

    // weight prep (tiny)
    prep_b<<<256, blk, 0, stream>>>(Wv,   Bv_hi, Bv_lo, 256);
    prep_b<<<384, blk, 0, stream>>>(Wo,   Bo_hi, Bo_lo, 384);
    prep_b<<<128, blk, 0, stream>>>(Wa,   Ba_hi, Ba_lo, 128);
    prep_b<<<256, blk, 0, stream>>>(Wout, Bw_hi, Bw_lo, 256);
    // activation prep
    prep_a<<<(n4 + 255) / 256, blk, 0, stream>>>(inp,   in_hi, in_lo, n4);
    prep_a<<<(n4 + 255) / 256, blk, 0, stream>>>(query, q_hi,  q_lo,  n4);

    const int MB = (LQ + 127) / 128;   // 293
    // value = input @ W_value + b (fp32 out, feeds sampler)
    gemm_mfma<0><<<dim3(256/64, MB), blk, 0, stream>>>(in_hi, in_lo, Bv_hi, Bv_lo, bv, value, LQ, 256);
    // attn logits = query @ W_attn + b (fp32 out)  [before off overwrites nothing; q still live]
    gemm_mfma<0><<<dim3(128/64, MB), blk, 0, stream>>>(q_hi, q_lo, Ba_hi, Ba_lo, ba, attn, LQ, 128);
    // off = query @ W_off + b (bf16 out, into regionA — in_hi/lo now dead)
    gemm_mfma<1><<<dim3(384/64, MB), blk, 0, stream>>>(q_hi, q_lo, Bo_hi, Bo_lo, bo, offb, LQ, 384);
    // sampling + softmax + weighted sum -> samp hi/lo bf16 (into regionB — q now dead)
    sample_kernel<<<dim3(LQ/4), blk, 0, stream>>>(refp, offb, attn, value, s_hi, s_lo);
    // out = samp @ W_out + b (fp32 out)
    gemm_mfma<0><<<dim3(256/64, MB), blk, 0, stream>>>(s_hi, s_lo, Bw_hi, Bw_lo, bout, (float*)d_out, LQ, 256);
}

// Round 5
// 409.005 us; speedup vs baseline: 1.5562x; 1.2141x over previous
//
#include <hip/hip_runtime.h>
#include <math.h>

// Problem constants (fixed by reference file)
#define LQ      37440
#define LIN     37440     // 32^3 + 16^3 + 8^3 + 4^3 (coincidentally == LQ)
#define DMODEL  256
#define NHEADS  8
#define CHEAD   32
#define K_DIM   256

typedef __attribute__((ext_vector_type(8))) short short8;
typedef __attribute__((ext_vector_type(4))) short short4v;
typedef __attribute__((ext_vector_type(4))) float f32x4;

__device__ inline unsigned short bf16_rte(float f) {
    union { float f; unsigned u; } v; v.f = f;
    return (unsigned short)((v.u + 0x7fffu + ((v.u >> 16) & 1u)) >> 16);
}
__device__ inline float bf16_f(unsigned short s) {
    union { unsigned u; float f; } v; v.u = ((unsigned)s) << 16;
    return v.f;
}
__device__ inline float bits_f(unsigned u) {
    union { unsigned u; float f; } v; v.u = u;
    return v.f;
}

// -------------------------------------------------------------------------
// prep_bf16: fp32 -> bf16 cast (n4 float4 groups)
// -------------------------------------------------------------------------
__global__ __launch_bounds__(256) void prep_bf16(const float* __restrict__ A,
        unsigned short* __restrict__ out, int n4)
{
    int i = blockIdx.x * 256 + threadIdx.x;
    if (i >= n4) return;
    float4 v = ((const float4*)A)[i];
    short4v h;
    h.x = (short)bf16_rte(v.x);
    h.y = (short)bf16_rte(v.y);
    h.z = (short)bf16_rte(v.z);
    h.w = (short)bf16_rte(v.w);
    ((short4v*)out)[i] = h;
}

// -------------------------------------------------------------------------
// prep_bt1: B (K=256 x N fp32) -> Bt (N x 256) bf16 (transposed, hi only)
// -------------------------------------------------------------------------
__global__ __launch_bounds__(256) void prep_bt1(const float* __restrict__ B,
        unsigned short* __restrict__ bt, int N)
{
    int i = blockIdx.x * 256 + threadIdx.x;
    int n = i >> 8, k = i & 255;
    if (n >= N) return;
    bt[(size_t)n * 256 + k] = bf16_rte(B[(size_t)k * N + n]);
}

// -------------------------------------------------------------------------
// prep_b3: B (K=256 x N fp32) -> Bt_hi/lo (N x 256 bf16) split
// -------------------------------------------------------------------------
__global__ __launch_bounds__(256) void prep_b3(const float* __restrict__ B,
        unsigned short* __restrict__ hi, unsigned short* __restrict__ lo, int N)
{
    int i = blockIdx.x * 256 + threadIdx.x;
    int n = i >> 8, k = i & 255;
    if (n >= N) return;
    float v = B[(size_t)k * N + n];
    unsigned short h = bf16_rte(v);
    hi[(size_t)n * 256 + k] = h;
    lo[(size_t)n * 256 + k] = bf16_rte(v - bf16_f(h));
}

__global__ void concat_bias(const float* __restrict__ a, const float* __restrict__ b,
                            float* __restrict__ dst)
{
    int t = threadIdx.x;  // 512 threads
    dst[t] = (t < 384) ? a[t] : b[t - 384];
}

// -------------------------------------------------------------------------
// Pure-bf16 MFMA GEMM: C = A @ Bt' + bias, bf16 out.
// A: M x 256 bf16 row-major; Bt: N x 256 bf16 (pre-transposed).
// BM=128, BN=64, BK=32, 256 thr = 4 waves, wave tile 32x64 (2x4 of 16x16x32).
// PERM=0: C row-major (M x N) bf16. PERM=1: value layout — col=(h*32+c)
//   writes to C[(h*LIN + row)*32 + c] (head-major volume, bf16).
// -------------------------------------------------------------------------
template<int PERM>
__global__ __launch_bounds__(256) void gemm_bf16s(
    const unsigned short* __restrict__ A, const unsigned short* __restrict__ Bt,
    const float* __restrict__ bias, unsigned short* __restrict__ Cout, int M, int N)
{
    __shared__ __align__(16) unsigned short As[128][40];
    __shared__ __align__(16) unsigned short Bs[64][40];

    const int t    = threadIdx.x;
    const int bm   = blockIdx.y * 128;
    const int bn   = blockIdx.x * 64;
    const int w    = t >> 6;
    const int lane = t & 63;
    const int lm   = lane & 15;
    const int quad = lane >> 4;

    // A staging: row t>>1, k-chunk (t&1)*16 shorts (two int4) -> 8KB
    const int a_row = t >> 1;
    const int a_k   = (t & 1) << 4;
    // B staging: row t>>2, k-chunk (t&3)*8 shorts (one int4) -> 4KB
    const int b_row = t >> 2;
    const int b_k   = (t & 3) << 3;

    int arow_g = bm + a_row; if (arow_g >= M) arow_g = M - 1;
    const size_t a_off = (size_t)arow_g * K_DIM + a_k;
    const size_t b_off = (size_t)(bn + b_row) * K_DIM + b_k;

    f32x4 acc[2][4];
    #pragma unroll
    for (int mt = 0; mt < 2; ++mt)
        #pragma unroll
        for (int nt = 0; nt < 4; ++nt)
            acc[mt][nt] = (f32x4){0.f, 0.f, 0.f, 0.f};

    for (int k0 = 0; k0 < K_DIM; k0 += 32) {
        int4 a0 = *(const int4*)(A + a_off + k0);
        int4 a1 = *(const int4*)(A + a_off + k0 + 8);
        int4 b0 = *(const int4*)(Bt + b_off + k0);
        __syncthreads();
        *(int4*)&As[a_row][a_k]     = a0;
        *(int4*)&As[a_row][a_k + 8] = a1;
        *(int4*)&Bs[b_row][b_k]     = b0;
        __syncthreads();

        short8 af[2], bf[4];
        #pragma unroll
        for (int mt = 0; mt < 2; ++mt)
            af[mt] = *(const short8*)&As[w * 32 + mt * 16 + lm][quad * 8];
        #pragma unroll
        for (int nt = 0; nt < 4; ++nt)
            bf[nt] = *(const short8*)&Bs[nt * 16 + lm][quad * 8];
        #pragma unroll
        for (int mt = 0; mt < 2; ++mt)
            #pragma unroll
            for (int nt = 0; nt < 4; ++nt)
                acc[mt][nt] = __builtin_amdgcn_mfma_f32_16x16x32_bf16(af[mt], bf[nt], acc[mt][nt], 0, 0, 0);
    }

    #pragma unroll
    for (int nt = 0; nt < 4; ++nt) {
        int col = bn + nt * 16 + lm;
        float bb = bias[col];
        #pragma unroll
        for (int mt = 0; mt < 2; ++mt)
            #pragma unroll
            for (int r = 0; r < 4; ++r) {
                int row = bm + w * 32 + mt * 16 + quad * 4 + r;
                if (row < M) {
                    float o = acc[mt][nt][r] + bb;
                    if (PERM) {
                        int h = col >> 5, c = col & 31;
                        Cout[((size_t)h * LIN + row) * 32 + c] = bf16_rte(o);
                    } else {
                        Cout[(size_t)row * N + col] = bf16_rte(o);
                    }
                }
            }
    }
}

// -------------------------------------------------------------------------
// Split-bf16 (3-MFMA) GEMM for the final projection: fp32 out.
// -------------------------------------------------------------------------
__global__ __launch_bounds__(256) void gemm_mfma3(
    const unsigned short* __restrict__ A_hi, const unsigned short* __restrict__ A_lo,
    const unsigned short* __restrict__ Bt_hi, const unsigned short* __restrict__ Bt_lo,
    const float* __restrict__ bias, float* __restrict__ Cout, int M, int N)
{
    __shared__ __align__(16) unsigned short As[2][128][40];
    __shared__ __align__(16) unsigned short Bs[2][64][40];

    const int t    = threadIdx.x;
    const int bm   = blockIdx.y * 128;
    const int bn   = blockIdx.x * 64;
    const int w    = t >> 6;
    const int lane = t & 63;
    const int lm   = lane & 15;
    const int quad = lane >> 4;

    const int a_row = t >> 1;
    const int a_k   = (t & 1) << 4;
    const int b_arr = t >> 7;
    const int b_row = (t & 127) >> 1;
    const int b_k   = (t & 1) << 4;

    int arow_g = bm + a_row; if (arow_g >= M) arow_g = M - 1;
    const size_t a_off = (size_t)arow_g * K_DIM + a_k;
    const size_t b_off = (size_t)(bn + b_row) * K_DIM + b_k;
    const unsigned short* Bsrc = b_arr ? Bt_lo : Bt_hi;

    f32x4 acc[2][4];
    #pragma unroll
    for (int mt = 0; mt < 2; ++mt)
        #pragma unroll
        for (int nt = 0; nt < 4; ++nt)
            acc[mt][nt] = (f32x4){0.f, 0.f, 0.f, 0.f};

    for (int k0 = 0; k0 < K_DIM; k0 += 32) {
        int4 ah0 = *(const int4*)(A_hi + a_off + k0);
        int4 ah1 = *(const int4*)(A_hi + a_off + k0 + 8);
        int4 al0 = *(const int4*)(A_lo + a_off + k0);
        int4 al1 = *(const int4*)(A_lo + a_off + k0 + 8);
        int4 bv0 = *(const int4*)(Bsrc + b_off + k0);
        int4 bv1 = *(const int4*)(Bsrc + b_off + k0 + 8);
        __syncthreads();
        *(int4*)&As[0][a_row][a_k]     = ah0;
        *(int4*)&As[0][a_row][a_k + 8] = ah1;
        *(int4*)&As[1][a_row][a_k]     = al0;
        *(int4*)&As[1][a_row][a_k + 8] = al1;
        *(int4*)&Bs[b_arr][b_row][b_k]     = bv0;
        *(int4*)&Bs[b_arr][b_row][b_k + 8] = bv1;
        __syncthreads();

        short8 af[2][2], bf[2][4];
        #pragma unroll
        for (int mt = 0; mt < 2; ++mt) {
            af[0][mt] = *(const short8*)&As[0][w * 32 + mt * 16 + lm][quad * 8];
            af[1][mt] = *(const short8*)&As[1][w * 32 + mt * 16 + lm][quad * 8];
        }
        #pragma unroll
        for (int nt = 0; nt < 4; ++nt) {
            bf[0][nt] = *(const short8*)&Bs[0][nt * 16 + lm][quad * 8];
            bf[1][nt] = *(const short8*)&Bs[1][nt * 16 + lm][quad * 8];
        }
        #pragma unroll
        for (int mt = 0; mt < 2; ++mt)
            #pragma unroll
            for (int nt = 0; nt < 4; ++nt) {
                acc[mt][nt] = __builtin_amdgcn_mfma_f32_16x16x32_bf16(af[0][mt], bf[0][nt], acc[mt][nt], 0, 0, 0);
                acc[mt][nt] = __builtin_amdgcn_mfma_f32_16x16x32_bf16(af[1][mt], bf[0][nt], acc[mt][nt], 0, 0, 0);
                acc[mt][nt] = __builtin_amdgcn_mfma_f32_16x16x32_bf16(af[0][mt], bf[1][nt], acc[mt][nt], 0, 0, 0);
            }
    }

    float bv4[4];
    #pragma unroll
    for (int nt = 0; nt < 4; ++nt) bv4[nt] = bias[bn + nt * 16 + lm];

    #pragma unroll
    for (int mt = 0; mt < 2; ++mt)
        #pragma unroll
        for (int nt = 0; nt < 4; ++nt)
            #pragma unroll
            for (int r = 0; r < 4; ++r) {
                int row = bm + w * 32 + mt * 16 + quad * 4 + r;
                if (row < M)
                    Cout[(size_t)row * N + bn + nt * 16 + lm] = acc[mt][nt][r] + bv4[nt];
            }
}

// -------------------------------------------------------------------------
// Sampling kernel v2: bf16 head-major value, precomputed corner
// weights/offsets in LDS ([c][hh] layout -> conflict-free phase-2 reads).
// Block = 256 threads = 4 queries x (8 heads x 8 channel-groups-of-4).
// qbuf: (LQ, 512) bf16 = [off(384) | attn logits(128)].
// -------------------------------------------------------------------------
__global__ __launch_bounds__(256) void sample_kernel(
    const float* __restrict__ refp,              // (LQ, 4, 3) fp32
    const unsigned short* __restrict__ qbuf,     // (LQ, 512) bf16
    const unsigned short* __restrict__ value_t,  // (8, LIN, 32) bf16 head-major
    unsigned short* __restrict__ samp_hi,        // (LQ, 256) bf16
    unsigned short* __restrict__ samp_lo)        // (LQ, 256) bf16
{
    __shared__ float4   wgtA[4][16][8];   // z=0: (y0x0,y0x1,y1x0,y1x1)   8 KB
    __shared__ float4   wgtB[4][16][8];   // z=1                          8 KB
    __shared__ int4     ozy4[4][16][8];   // (z0y0,z0y1,z1y0,z1y1)*32     8 KB
    __shared__ unsigned oxx_[4][16][8];   // x0*32 | (x1*32)<<16          2 KB
    __shared__ float    aw_ [4][16][8];   // softmax weight               2 KB
    __shared__ float    lg  [4][128];     // logits                       2 KB

    const int t  = threadIdx.x;
    const int q0 = blockIdx.x * 4;

    const int   Sz[4]   = {32, 16, 8, 4};
    const float invS[4] = {1.f/32.f, 1.f/16.f, 1.f/8.f, 1.f/4.f};
    const int   St[4]   = {0, 32768, 36864, 37376};

    // Phase 1: geometry -> 8 trilinear weights (validity folded) + offsets
    #pragma unroll
    for (int pi = t; pi < 512; pi += 256) {
        int ql = pi >> 7;
        int hp = pi & 127;          // hh*16 + c, c = l*4+p
        int hh = hp >> 4;
        int c  = hp & 15;
        int l  = c >> 2;
        int q  = q0 + ql;
        const unsigned short* o = qbuf + (size_t)q * 512 + hp * 3;
        const float* r = refp + q * 12 + l * 3;
        const int   S  = Sz[l];
        const float Sf = (float)S;
        const float is = invS[l];
        float ix = (r[0] + bf16_f(o[0]) * is) * Sf - 0.5f;
        float iy = (r[1] + bf16_f(o[1]) * is) * Sf - 0.5f;
        float iz = (r[2] + bf16_f(o[2]) * is) * Sf - 0.5f;
        float xf = floorf(ix), yf = floorf(iy), zf = floorf(iz);
        float fx = ix - xf, fy = iy - yf, fz = iz - zf;
        int x0 = (int)xf, y0 = (int)yf, z0 = (int)zf;

        float wx0 = (x0 >= 0  && x0 < S)     ? (1.f - fx) : 0.f;
        float wx1 = (x0 >= -1 && x0 < S - 1) ? fx         : 0.f;
        float wy0 = (y0 >= 0  && y0 < S)     ? (1.f - fy) : 0.f;
        float wy1 = (y0 >= -1 && y0 < S - 1) ? fy         : 0.f;
        float wz0 = (z0 >= 0  && z0 < S)     ? (1.f - fz) : 0.f;
        float wz1 = (z0 >= -1 && z0 < S - 1) ? fz         : 0.f;

        int cx0 = min(max(x0, 0), S - 1), cx1 = min(max(x0 + 1, 0), S - 1);
        int cy0 = min(max(y0, 0), S - 1), cy1 = min(max(y0 + 1, 0), S - 1);
        int cz0 = min(max(z0, 0), S - 1), cz1 = min(max(z0 + 1, 0), S - 1);

        const int S2 = S * S;
        const int st = St[l];
        wgtA[ql][c][hh] = make_float4(wz0*wy0*wx0, wz0*wy0*wx1, wz0*wy1*wx0, wz0*wy1*wx1);
        wgtB[ql][c][hh] = make_float4(wz1*wy0*wx0, wz1*wy0*wx1, wz1*wy1*wx0, wz1*wy1*wx1);
        ozy4[ql][c][hh] = make_int4((st + cz0*S2 + cy0*S) * 32,
                                    (st + cz0*S2 + cy1*S) * 32,
                                    (st + cz1*S2 + cy0*S) * 32,
                                    (st + cz1*S2 + cy1*S) * 32);
        oxx_[ql][c][hh] = (unsigned)(cx0 * 32) | ((unsigned)(cx1 * 32) << 16);
        lg[ql][hp] = bf16_f(qbuf[(size_t)q * 512 + 384 + hp]);
    }
    __syncthreads();

    // Phase 1b: softmax over 16 points per (q_local, head)
    #pragma unroll
    for (int pi = t; pi < 512; pi += 256) {
        int ql = pi >> 7;
        int hp = pi & 127;
        int hh = hp >> 4;
        int c  = hp & 15;
        const float* L = &lg[ql][hh << 4];
        float m = L[0];
        #pragma unroll
        for (int j = 1; j < 16; ++j) m = fmaxf(m, L[j]);
        float s = 0.f;
        #pragma unroll
        for (int j = 0; j < 16; ++j) s += expf(L[j] - m);
        aw_[ql][c][hh] = expf(lg[ql][hp] - m) / s;
    }
    __syncthreads();

    // Phase 2: gather + weighted accumulate. 64 threads per query.
    const int ql   = t >> 6;
    const int lane = t & 63;
    const int hh   = lane >> 3;
    const int cg   = (lane & 7) << 2;
    const int q    = q0 + ql;
    const unsigned short* vt = value_t + (size_t)hh * LIN * 32 + cg;

    float ax = 0.f, ay = 0.f, az = 0.f, aw = 0.f;

    #pragma unroll
    for (int c = 0; c < 16; ++c) {
        float4 wA = wgtA[ql][c][hh];
        float4 wB = wgtB[ql][c][hh];
        int4   zy = ozy4[ql][c][hh];
        unsigned xx = oxx_[ql][c][hh];
        float  a  = aw_[ql][c][hh];
        int x0 = (int)(xx & 0xffffu), x1 = (int)(xx >> 16);
        wA.x *= a; wA.y *= a; wA.z *= a; wA.w *= a;
        wB.x *= a; wB.y *= a; wB.z *= a; wB.w *= a;

        #define CORNER(OFF, W) { \
            uint2 uv = *(const uint2*)(vt + (OFF)); \
            ax += (W) * bits_f(uv.x << 16); \
            ay += (W) * bits_f(uv.x & 0xffff0000u); \
            az += (W) * bits_f(uv.y << 16); \
            aw += (W) * bits_f(uv.y & 0xffff0000u); }

        CORNER(zy.x + x0, wA.x); CORNER(zy.x + x1, wA.y);
        CORNER(zy.y + x0, wA.z); CORNER(zy.y + x1, wA.w);
        CORNER(zy.z + x0, wB.x); CORNER(zy.z + x1, wB.y);
        CORNER(zy.w + x0, wB.z); CORNER(zy.w + x1, wB.w);
        #undef CORNER
    }

    // hi/lo split epilogue
    short4v oh, ol;
    unsigned short s;
    s = bf16_rte(ax); oh.x = (short)s; ol.x = (short)bf16_rte(ax - bf16_f(s));
    s = bf16_rte(ay); oh.y = (short)s; ol.y = (short)bf16_rte(ay - bf16_f(s));
    s = bf16_rte(az); oh.z = (short)s; ol.z = (short)bf16_rte(az - bf16_f(s));
    s = bf16_rte(aw); oh.w = (short)s; ol.w = (short)bf16_rte(aw - bf16_f(s));
    size_t oidx = (size_t)q * DMODEL + hh * CHEAD + cg;
    *(short4v*)(samp_hi + oidx) = oh;
    *(short4v*)(samp_lo + oidx) = ol;
}

// -------------------------------------------------------------------------
// Workspace (~96 MB):
//   value_t bf16 (8,LIN,32)         19.2 MB
//   qbuf bf16 (LQ,512)              38.3 MB
//   regionA: in_b -> s_hi           19.2 MB
//   regionB: q_b  -> s_lo           19.2 MB
//   weights + bias                  ~0.6 MB
// -------------------------------------------------------------------------
extern "C" void kernel_launch(void* const* d_in, const int* in_sizes, int n_in,
                              void* d_out, int out_size, void* d_ws, size_t ws_size,
                              hipStream_t stream) {
    const float* query = (const float*)d_in[0];
    const float* refp  = (const float*)d_in[1];
    const float* inp   = (const float*)d_in[2];
    const float* Wv   = (const float*)d_in[5];
    const float* bv   = (const float*)d_in[6];
    const float* Wo   = (const float*)d_in[7];
    const float* bo   = (const float*)d_in[8];
    const float* Wa   = (const float*)d_in[9];
    const float* ba   = (const float*)d_in[10];
    const float* Wout = (const float*)d_in[11];
    const float* bout = (const float*)d_in[12];

    char* p = (char*)d_ws;
    unsigned short* value_t = (unsigned short*)p; p += (size_t)LQ * 256 * 2;
    unsigned short* qbuf    = (unsigned short*)p; p += (size_t)LQ * 512 * 2;
    unsigned short* regionA = (unsigned short*)p; p += (size_t)LQ * 256 * 2;
    unsigned short* regionB = (unsigned short*)p; p += (size_t)LQ * 256 * 2;
    unsigned short* Bv    = (unsigned short*)p;   p += 256 * 256 * 2;
    unsigned short* Bq    = (unsigned short*)p;   p += 512 * 256 * 2;
    unsigned short* Bw_hi = (unsigned short*)p;   p += 256 * 256 * 2;
    unsigned short* Bw_lo = (unsigned short*)p;   p += 256 * 256 * 2;
    float* bias_m = (float*)p;                    p += 512 * 4;

    unsigned short* in_b = regionA;   // dead after value GEMM
    unsigned short* q_b  = regionB;   // dead after qbuf GEMM
    unsigned short* s_hi = regionA;   // written by sampler
    unsigned short* s_lo = regionB;

    const int n4 = LQ * 256 / 4;   // 2,396,160 -> 9360 blocks
    dim3 blk(256);

    prep_bf16<<<n4 / 256, blk, 0, stream>>>(inp,   in_b, n4);
    prep_bf16<<<n4 / 256, blk, 0, stream>>>(query, q_b,  n4);
    prep_bt1<<<256, blk, 0, stream>>>(Wv, Bv, 256);
    prep_bt1<<<384, blk, 0, stream>>>(Wo, Bq, 384);
    prep_bt1<<<128, blk, 0, stream>>>(Wa, Bq + 384 * 256, 128);
    prep_b3 <<<256, blk, 0, stream>>>(Wout, Bw_hi, Bw_lo, 256);
    concat_bias<<<1, 512, 0, stream>>>(bo, ba, bias_m);

    const int MB = (LQ + 127) / 128;   // 293
    // value (head-major permuted, bf16)
    gemm_bf16s<1><<<dim3(4, MB), blk, 0, stream>>>(in_b, Bv, bv, value_t, LQ, 256);
    // off + attn logits (merged, bf16)
    gemm_bf16s<0><<<dim3(8, MB), blk, 0, stream>>>(q_b, Bq, bias_m, qbuf, LQ, 512);
    // sampling + softmax + weighted sum -> samp hi/lo
    sample_kernel<<<LQ / 4, blk, 0, stream>>>(refp, qbuf, value_t, s_hi, s_lo);
    // out = samp @ W_out + b (split 3-MFMA, fp32 out)
    gemm_mfma3<<<dim3(4, MB), blk, 0, stream>>>(s_hi, s_lo, Bw_hi, Bw_lo, bout, (float*)d_out, LQ, 256);
}

// Round 6
// 378.816 us; speedup vs baseline: 1.6802x; 1.0797x over previous
//
#include <hip/hip_runtime.h>
#include <math.h>

// Problem constants (fixed by reference file)
#define LQ      37440
#define LIN     37440     // 32^3 + 16^3 + 8^3 + 4^3
#define DMODEL  256
#define NHEADS  8
#define CHEAD   32
#define K_DIM   256

typedef __attribute__((ext_vector_type(8))) short short8;
typedef __attribute__((ext_vector_type(4))) short short4v;
typedef __attribute__((ext_vector_type(4))) float f32x4;
typedef __attribute__((ext_vector_type(2))) float f32x2;

__device__ inline unsigned short bf16_rte(float f) {
    union { float f; unsigned u; } v; v.f = f;
    return (unsigned short)((v.u + 0x7fffu + ((v.u >> 16) & 1u)) >> 16);
}
__device__ inline float bf16_f(unsigned short s) {
    union { unsigned u; float f; } v; v.u = ((unsigned)s) << 16;
    return v.f;
}
__device__ inline float bits_f(unsigned u) {
    union { unsigned u; float f; } v; v.u = u;
    return v.f;
}
__device__ inline unsigned pkbf(float a, float b) {
    return (unsigned)bf16_rte(a) | ((unsigned)bf16_rte(b) << 16);
}

// -------------------------------------------------------------------------
// prep_bt1: B (K=256 x N fp32) -> Bt (N x 256) bf16 (transposed)
// -------------------------------------------------------------------------
__global__ __launch_bounds__(256) void prep_bt1(const float* __restrict__ B,
        unsigned short* __restrict__ bt, int N)
{
    int i = blockIdx.x * 256 + threadIdx.x;
    int n = i >> 8, k = i & 255;
    if (n >= N) return;
    bt[(size_t)n * 256 + k] = bf16_rte(B[(size_t)k * N + n]);
}

__global__ void concat_bias(const float* __restrict__ a, const float* __restrict__ b,
                            float* __restrict__ dst)
{
    int t = threadIdx.x;  // 512 threads
    dst[t] = (t < 384) ? a[t] : b[t - 384];
}

// -------------------------------------------------------------------------
// bf16 MFMA GEMM with fused A conversion.
// AF32: A is fp32 (convert during staging) else bf16.
// PERM: head-major value output layout. OUTF32: fp32 C (final projection).
// BM=128, BN=64, BK=32, 256 thr = 4 waves, wave tile 32x64 (2x4 of 16x16x32).
// -------------------------------------------------------------------------
template<int AF32, int PERM, int OUTF32>
__global__ __launch_bounds__(256) void gemm_k(
    const void* __restrict__ A, const unsigned short* __restrict__ Bt,
    const float* __restrict__ bias, void* __restrict__ Cout, int M, int N)
{
    __shared__ __align__(16) unsigned short As[128][40];
    __shared__ __align__(16) unsigned short Bs[64][40];

    const int t    = threadIdx.x;
    const int bm   = blockIdx.y * 128;
    const int bn   = blockIdx.x * 64;
    const int w    = t >> 6;
    const int lane = t & 63;
    const int lm   = lane & 15;
    const int quad = lane >> 4;

    // A staging: row t>>1, k-chunk (t&1)*16 elements
    const int a_row = t >> 1;
    const int a_k   = (t & 1) << 4;
    // B staging: row t>>2, k-chunk (t&3)*8 elements (one int4)
    const int b_row = t >> 2;
    const int b_k   = (t & 3) << 3;

    int arow_g = bm + a_row; if (arow_g >= M) arow_g = M - 1;
    const size_t a_off = (size_t)arow_g * K_DIM + a_k;
    const size_t b_off = (size_t)(bn + b_row) * K_DIM + b_k;

    f32x4 acc[2][4];
    #pragma unroll
    for (int mt = 0; mt < 2; ++mt)
        #pragma unroll
        for (int nt = 0; nt < 4; ++nt)
            acc[mt][nt] = (f32x4){0.f, 0.f, 0.f, 0.f};

    for (int k0 = 0; k0 < K_DIM; k0 += 32) {
        int4 s0, s1;
        if (AF32) {
            const float* Af = (const float*)A;
            float4 f0 = *(const float4*)(Af + a_off + k0);
            float4 f1 = *(const float4*)(Af + a_off + k0 + 4);
            float4 f2 = *(const float4*)(Af + a_off + k0 + 8);
            float4 f3 = *(const float4*)(Af + a_off + k0 + 12);
            s0 = make_int4((int)pkbf(f0.x, f0.y), (int)pkbf(f0.z, f0.w),
                           (int)pkbf(f1.x, f1.y), (int)pkbf(f1.z, f1.w));
            s1 = make_int4((int)pkbf(f2.x, f2.y), (int)pkbf(f2.z, f2.w),
                           (int)pkbf(f3.x, f3.y), (int)pkbf(f3.z, f3.w));
        } else {
            const unsigned short* Ab = (const unsigned short*)A;
            s0 = *(const int4*)(Ab + a_off + k0);
            s1 = *(const int4*)(Ab + a_off + k0 + 8);
        }
        int4 b0 = *(const int4*)(Bt + b_off + k0);
        __syncthreads();
        *(int4*)&As[a_row][a_k]     = s0;
        *(int4*)&As[a_row][a_k + 8] = s1;
        *(int4*)&Bs[b_row][b_k]     = b0;
        __syncthreads();

        short8 af[2], bf[4];
        #pragma unroll
        for (int mt = 0; mt < 2; ++mt)
            af[mt] = *(const short8*)&As[w * 32 + mt * 16 + lm][quad * 8];
        #pragma unroll
        for (int nt = 0; nt < 4; ++nt)
            bf[nt] = *(const short8*)&Bs[nt * 16 + lm][quad * 8];
        #pragma unroll
        for (int mt = 0; mt < 2; ++mt)
            #pragma unroll
            for (int nt = 0; nt < 4; ++nt)
                acc[mt][nt] = __builtin_amdgcn_mfma_f32_16x16x32_bf16(af[mt], bf[nt], acc[mt][nt], 0, 0, 0);
    }

    #pragma unroll
    for (int nt = 0; nt < 4; ++nt) {
        int col = bn + nt * 16 + lm;
        float bb = bias[col];
        #pragma unroll
        for (int mt = 0; mt < 2; ++mt)
            #pragma unroll
            for (int r = 0; r < 4; ++r) {
                int row = bm + w * 32 + mt * 16 + quad * 4 + r;
                if (row < M) {
                    float o = acc[mt][nt][r] + bb;
                    if (OUTF32) {
                        ((float*)Cout)[(size_t)row * N + col] = o;
                    } else if (PERM) {
                        int h = col >> 5, c = col & 31;
                        ((unsigned short*)Cout)[((size_t)h * LIN + row) * 32 + c] = bf16_rte(o);
                    } else {
                        ((unsigned short*)Cout)[(size_t)row * N + col] = bf16_rte(o);
                    }
                }
            }
    }
}

// -------------------------------------------------------------------------
// Sampling kernel v3: x-corner pair fusion.
// 64 lanes per query = 8 heads x 8 lanes. Lane j (0..7) of a head loads
// int4 (8 ch) at span-offset j*8 shorts of the 128B [x0|x1] voxel pair;
// j<4 covers x0 channels (j&3)*8.., j>=4 covers x1. Combined via shfl_xor(4).
// OOB x handled by zero weights + workspace padding (y/z clamped).
// qbuf: (LQ, 512) bf16 = [off(384) | attn logits(128)]. samp bf16 out.
// -------------------------------------------------------------------------
__global__ __launch_bounds__(256) void sample_kernel(
    const float* __restrict__ refp,              // (LQ, 4, 3) fp32
    const unsigned short* __restrict__ qbuf,     // (LQ, 512) bf16
    const unsigned short* __restrict__ value_t,  // (8, LIN, 32) bf16 head-major
    unsigned short* __restrict__ samp)           // (LQ, 256) bf16
{
    __shared__ float4 zywS[4][16][8];   // zy corner cross-weights   8 KB
    __shared__ f32x2  wxS [4][16][8];   // (wx0, wx1) * a            4 KB
    __shared__ int4   ozyS[4][16][8];   // zy offsets * 32 (shorts)  8 KB
    __shared__ int    xbS [4][16][8];   // x0 * 32 (shorts, signed)  2 KB
    __shared__ float  lg  [4][128];     // logits                    2 KB

    const int t  = threadIdx.x;
    const int q0 = blockIdx.x * 4;

    const int   Sz[4]   = {32, 16, 8, 4};
    const float invS[4] = {1.f/32.f, 1.f/16.f, 1.f/8.f, 1.f/4.f};
    const int   St[4]   = {0, 32768, 36864, 37376};

    // Phase 1: geometry
    #pragma unroll
    for (int pi = t; pi < 512; pi += 256) {
        int ql = pi >> 7;
        int hp = pi & 127;          // hh*16 + c, c = l*4+p
        int hh = hp >> 4;
        int c  = hp & 15;
        int l  = c >> 2;
        int q  = q0 + ql;
        const unsigned short* o = qbuf + (size_t)q * 512 + hp * 3;
        const float* r = refp + q * 12 + l * 3;
        const int   S  = Sz[l];
        const float Sf = (float)S;
        const float is = invS[l];
        float ix = (r[0] + bf16_f(o[0]) * is) * Sf - 0.5f;
        float iy = (r[1] + bf16_f(o[1]) * is) * Sf - 0.5f;
        float iz = (r[2] + bf16_f(o[2]) * is) * Sf - 0.5f;
        float xf = floorf(ix), yf = floorf(iy), zf = floorf(iz);
        float fx = ix - xf, fy = iy - yf, fz = iz - zf;
        int x0 = (int)xf, y0 = (int)yf, z0 = (int)zf;

        float wx0 = (x0 >= 0  && x0 < S)     ? (1.f - fx) : 0.f;
        float wx1 = (x0 >= -1 && x0 < S - 1) ? fx         : 0.f;
        float wy0 = (y0 >= 0  && y0 < S)     ? (1.f - fy) : 0.f;
        float wy1 = (y0 >= -1 && y0 < S - 1) ? fy         : 0.f;
        float wz0 = (z0 >= 0  && z0 < S)     ? (1.f - fz) : 0.f;
        float wz1 = (z0 >= -1 && z0 < S - 1) ? fz         : 0.f;

        int cy0 = min(max(y0, 0), S - 1), cy1 = min(max(y0 + 1, 0), S - 1);
        int cz0 = min(max(z0, 0), S - 1), cz1 = min(max(z0 + 1, 0), S - 1);

        const int S2 = S * S;
        const int st = St[l];
        zywS[ql][c][hh] = make_float4(wz0*wy0, wz0*wy1, wz1*wy0, wz1*wy1);
        wxS [ql][c][hh] = (f32x2){wx0, wx1};
        ozyS[ql][c][hh] = make_int4((st + cz0*S2 + cy0*S) * 32,
                                    (st + cz0*S2 + cy1*S) * 32,
                                    (st + cz1*S2 + cy0*S) * 32,
                                    (st + cz1*S2 + cy1*S) * 32);
        xbS [ql][c][hh] = x0 * 32;   // may be -32 .. (S-1)*32
        lg[ql][hp] = bf16_f(qbuf[(size_t)q * 512 + 384 + hp]);
    }
    __syncthreads();

    // Phase 1b: softmax over 16 points per (q_local, head); fold a into wx
    #pragma unroll
    for (int pi = t; pi < 512; pi += 256) {
        int ql = pi >> 7;
        int hp = pi & 127;
        int hh = hp >> 4;
        int c  = hp & 15;
        const float* L = &lg[ql][hh << 4];
        float m = L[0];
        #pragma unroll
        for (int j = 1; j < 16; ++j) m = fmaxf(m, L[j]);
        float s = 0.f;
        #pragma unroll
        for (int j = 0; j < 16; ++j) s += expf(L[j] - m);
        float a = expf(lg[ql][hp] - m) / s;
        f32x2 wv = wxS[ql][c][hh];
        wxS[ql][c][hh] = (f32x2){wv.x * a, wv.y * a};
    }
    __syncthreads();

    // Phase 2: gather + weighted accumulate. 64 lanes = 8 heads x 8 lanes.
    const int ql   = t >> 6;
    const int lane = t & 63;
    const int hh   = lane >> 3;
    const int j    = lane & 7;
    const int xsel = j >> 2;          // 0: x0 half, 1: x1 half
    const int cgrp = (j & 3) << 3;    // output channel group base (8 ch)
    const int q    = q0 + ql;
    const unsigned short* vt = value_t + (size_t)hh * LIN * 32 + j * 8;

    f32x2 acc0 = {0.f,0.f}, acc1 = {0.f,0.f}, acc2 = {0.f,0.f}, acc3 = {0.f,0.f};

    #pragma unroll
    for (int c = 0; c < 16; ++c) {
        float4 zyw = zywS[ql][c][hh];
        f32x2  wx  = wxS [ql][c][hh];
        int4   zo  = ozyS[ql][c][hh];
        int    xb  = xbS [ql][c][hh];
        float  ws  = xsel ? wx.y : wx.x;
        const unsigned short* bp = vt + xb;

        #define CORNER(OFF, WZ) { \
            int4 v = *(const int4*)(bp + (OFF)); \
            float w_ = (WZ) * ws; \
            f32x2 w2 = {w_, w_}; \
            acc0 += w2 * (f32x2){bits_f(((unsigned)v.x) << 16), bits_f((unsigned)v.x & 0xffff0000u)}; \
            acc1 += w2 * (f32x2){bits_f(((unsigned)v.y) << 16), bits_f((unsigned)v.y & 0xffff0000u)}; \
            acc2 += w2 * (f32x2){bits_f(((unsigned)v.z) << 16), bits_f((unsigned)v.z & 0xffff0000u)}; \
            acc3 += w2 * (f32x2){bits_f(((unsigned)v.w) << 16), bits_f((unsigned)v.w & 0xffff0000u)}; }

        CORNER(zo.x, zyw.x);
        CORNER(zo.y, zyw.y);
        CORNER(zo.z, zyw.z);
        CORNER(zo.w, zyw.w);
        #undef CORNER
    }

    // Combine x0/x1 halves across lane^4, pack to bf16, store (lanes j<4)
    float c0 = acc0.x + __shfl_xor(acc0.x, 4);
    float c1 = acc0.y + __shfl_xor(acc0.y, 4);
    float c2 = acc1.x + __shfl_xor(acc1.x, 4);
    float c3 = acc1.y + __shfl_xor(acc1.y, 4);
    float c4 = acc2.x + __shfl_xor(acc2.x, 4);
    float c5 = acc2.y + __shfl_xor(acc2.y, 4);
    float c6 = acc3.x + __shfl_xor(acc3.x, 4);
    float c7 = acc3.y + __shfl_xor(acc3.y, 4);
    if (xsel == 0) {
        int4 o = make_int4((int)pkbf(c0, c1), (int)pkbf(c2, c3),
                           (int)pkbf(c4, c5), (int)pkbf(c6, c7));
        *(int4*)(samp + (size_t)q * DMODEL + hh * CHEAD + cgrp) = o;
    }
}

// -------------------------------------------------------------------------
// Workspace (~77 MB):
//   pad 256 B (x-span underflow guard)
//   value_t bf16 (8,LIN,32)         19.2 MB
//   qbuf bf16 (LQ,512)              38.3 MB
//   samp bf16 (LQ,256)              19.2 MB
//   weights + bias                  ~0.55 MB
// -------------------------------------------------------------------------
extern "C" void kernel_launch(void* const* d_in, const int* in_sizes, int n_in,
                              void* d_out, int out_size, void* d_ws, size_t ws_size,
                              hipStream_t stream) {
    const float* query = (const float*)d_in[0];
    const float* refp  = (const float*)d_in[1];
    const float* inp   = (const float*)d_in[2];
    const float* Wv   = (const float*)d_in[5];
    const float* bv   = (const float*)d_in[6];
    const float* Wo   = (const float*)d_in[7];
    const float* bo   = (const float*)d_in[8];
    const float* Wa   = (const float*)d_in[9];
    const float* ba   = (const float*)d_in[10];
    const float* Wout = (const float*)d_in[11];
    const float* bout = (const float*)d_in[12];

    char* p = (char*)d_ws;
    p += 256;                                     // underflow pad
    unsigned short* value_t = (unsigned short*)p; p += (size_t)LIN * 256 * 2;
    unsigned short* qbuf    = (unsigned short*)p; p += (size_t)LQ * 512 * 2;
    unsigned short* samp    = (unsigned short*)p; p += (size_t)LQ * 256 * 2;
    unsigned short* Bv   = (unsigned short*)p;    p += 256 * 256 * 2;
    unsigned short* Bq   = (unsigned short*)p;    p += 512 * 256 * 2;
    unsigned short* Bw   = (unsigned short*)p;    p += 256 * 256 * 2;
    float* bias_m = (float*)p;                    p += 512 * 4;

    dim3 blk(256);

    prep_bt1<<<256, blk, 0, stream>>>(Wv,   Bv, 256);
    prep_bt1<<<384, blk, 0, stream>>>(Wo,   Bq, 384);
    prep_bt1<<<128, blk, 0, stream>>>(Wa,   Bq + 384 * 256, 128);
    prep_bt1<<<256, blk, 0, stream>>>(Wout, Bw, 256);
    concat_bias<<<1, 512, 0, stream>>>(bo, ba, bias_m);

    const int MB = (LQ + 127) / 128;   // 293
    // value (fp32 A fused-cast, head-major bf16 out)
    gemm_k<1,1,0><<<dim3(4, MB), blk, 0, stream>>>(inp, Bv, bv, value_t, LQ, 256);
    // off + attn logits merged (fp32 A fused-cast, bf16 out)
    gemm_k<1,0,0><<<dim3(8, MB), blk, 0, stream>>>(query, Bq, bias_m, qbuf, LQ, 512);
    // sampling + softmax + weighted sum -> samp bf16
    sample_kernel<<<LQ / 4, blk, 0, stream>>>(refp, qbuf, value_t, samp);
    // out = samp @ W_out + b (bf16 A, fp32 out)
    gemm_k<0,0,1><<<dim3(4, MB), blk, 0, stream>>>(samp, Bw, bout, d_out, LQ, 256);
}